// Round 8
// baseline (156.312 us; speedup 1.0000x reference)
//
#include <hip/hip_runtime.h>

// LinearConv2D fused v8: v7 (t-split, 8 blocks/CU) with the global_load_lds
// EXEC-mask bug fixed: staging loads are unconditional; OOB lanes source from
// a zero-filled __device__ array (per-lane SOURCE select is legal; per-lane
// DEST masking is not, because LDS dest = readfirstlane(base) + lane*16).
// x[8,128,32,1024] f32, weight[128,16,32,16] f32 -> out[8,128,17,257] f32
// y[n,t] = sum_{f in {2fo-1,2fo}} sum_{d,w} x[b,g16+d,f,4t+w-8]*wt[g16+n,d,f,w]
// Grid (fo, g, b*2+th) = 2176 blocks; block = 256 thr = 4 waves.
// Slice = (f,d-pair) x tau[512th-8, 512th+536) as [2 rows][544 f32];
// ring of 4 slots staged 3 ahead, counted vmcnt across raw s_barriers (v6
// schedule, verified). Wave wid owns t = 128th + 16*(2wid+tt) + cc.

typedef __attribute__((ext_vector_type(8))) short short8v;
typedef __attribute__((ext_vector_type(4))) float f32x4;

#define TPB 256

__device__ __attribute__((aligned(64))) float g_zeros[16];   // BSS: all-zero

static __device__ __forceinline__ short f2bf(float f) {   // RNE f32->bf16
    unsigned u = __builtin_bit_cast(unsigned, f);
    u += 0x7FFFu + ((u >> 16) & 1u);
    return (short)(u >> 16);
}

__global__ __launch_bounds__(TPB, 8) void lconv8(
    const float* __restrict__ x,   // [8,128,32,1024]
    const float* __restrict__ wt,  // [128,16,32,16]
    float* __restrict__ out)       // [8,128,17,257]
{
    __shared__ __attribute__((aligned(16))) float xl[4352]; // 4 slots x 1088
    __shared__ float red[4][16];

    const int fo = blockIdx.x, g = blockIdx.y;
    const int b  = blockIdx.z >> 1, th = blockIdx.z & 1;
    const int tid  = threadIdx.x;
    const int lane = tid & 63;
    const int wid  = __builtin_amdgcn_readfirstlane(tid >> 6);
    const int cc = lane & 15;          // fragment column (t or n)
    const int kq = lane >> 4;          // k-group 0..3

    int fvals[2]; int nf = 0;
    if (2*fo - 1 >= 0) fvals[nf++] = 2*fo - 1;
    if (2*fo < 32)     fvals[nf++] = 2*fo;
    const int f0 = fvals[0];
    const int f1 = (nf > 1) ? fvals[1] : f0;

    const int BG = b*128 + g*16;
    const int wlc = (g*16 + cc)*8192 + (kq>>1)*512 + 8*(kq&1);
    // slice-local read base: row(kq>>1)*544 + 4cc + 8*(kq&1) + 128*wid (+64*tt+j)
    const int rbase = (kq>>1)*544 + 4*cc + 8*(kq&1) + 128*wid;

    // stage one (f, d-pair) half-slice into ring slot; 2 VM instr per wave,
    // every wave, unconditional exec on pass A (lane0 of each wave active).
    // chunk c: row r = c>=136, c16 = c-136r, tau0 = 4*c16 - 8 + 512*th;
    // OOB chunks (left/right window pad) DMA zeros from g_zeros.
    auto stage2 = [&](int f_, int dp_, int slot_) {
        {   // pass A: chunks 0..255
            const int c   = tid;
            const int r   = (c >= 136) ? 1 : 0;
            const int c16 = c - r*136;
            const int tau0 = 4*c16 - 8 + 512*th;
            const bool ok = (tau0 >= 0) & (tau0 <= 1020);
            const float* src = ok
                ? (x + ((size_t)((BG + 2*dp_ + r)*32 + f_))*1024 + tau0)
                : g_zeros;
            __builtin_amdgcn_global_load_lds(
                (const __attribute__((address_space(1))) void*)src,
                (__attribute__((address_space(3))) void*)&xl[slot_*1088 + 4*c],
                16, 0, 0);
        }
        {   // pass B: chunks 256..271 (row-1 tail), lanes 0..15 of EVERY wave
            // (idempotent identical writes; lane 0 active -> base correct)
            const int c16 = 120 + (lane & 15);
            const int tau0 = 4*c16 - 8 + 512*th;
            const bool ok = (tau0 >= 0) & (tau0 <= 1020);
            const float* src = ok
                ? (x + ((size_t)((BG + 2*dp_ + 1)*32 + f_))*1024 + tau0)
                : g_zeros;
            if (lane < 16)
                __builtin_amdgcn_global_load_lds(
                    (const __attribute__((address_space(1))) void*)src,
                    (__attribute__((address_space(3))) void*)&xl[slot_*1088 + 4*(256 + lane)],
                    16, 0, 0);
        }
    };

    // prologue: stage slices 0,1,2 (all f0)
    stage2(f0, 0, 0);
    stage2(f0, 1, 1);
    stage2(f0, 2, 2);

    f32x4 acc[2];
    acc[0] = (f32x4){0.f, 0.f, 0.f, 0.f};
    acc[1] = (f32x4){0.f, 0.f, 0.f, 0.f};

    __syncthreads();   // drains prologue

    short8v afr[8];

    for (int s = 0; s < nf; ++s) {
        const int f = (s == 0) ? f0 : f1;

        // A-frags for this f: 8 d-pairs, 32B/lane (L1/L2-hot). Compiler's own
        // waitcnt for these retires them without draining the 6 slice DMAs.
        #pragma unroll
        for (int dp = 0; dp < 8; ++dp) {
            const float* wp = wt + wlc + dp*1024 + f*16;
            const float4 w0 = *(const float4*)wp;
            const float4 w1 = *(const float4*)(wp + 4);
            union { short8v s8; short h[8]; } u;
            u.h[0]=f2bf(w0.x); u.h[1]=f2bf(w0.y); u.h[2]=f2bf(w0.z); u.h[3]=f2bf(w0.w);
            u.h[4]=f2bf(w1.x); u.h[5]=f2bf(w1.y); u.h[6]=f2bf(w1.z); u.h[7]=f2bf(w1.w);
            afr[dp] = u.s8;
        }

        const bool tail = (s == nf - 1);
        #pragma unroll
        for (int dp = 0; dp < 8; ++dp) {
            // counted wait: retire own slice-q loads; keep q+1..q+3 in flight
            if (tail && dp == 6)      asm volatile("s_waitcnt vmcnt(2)" ::: "memory");
            else if (tail && dp == 7) asm volatile("s_waitcnt vmcnt(0)" ::: "memory");
            else                      asm volatile("s_waitcnt vmcnt(4)" ::: "memory");
            __builtin_amdgcn_sched_barrier(0);
            __builtin_amdgcn_s_barrier();

            const float* xp = xl + (dp & 3)*1088 + rbase;
            #pragma unroll
            for (int tt = 0; tt < 2; ++tt) {
                const float4 a0 = *(const float4*)(xp + 64*tt);
                const float4 a1 = *(const float4*)(xp + 64*tt + 4);
                union { short8v s8; short h[8]; } ub;
                ub.h[0]=f2bf(a0.x); ub.h[1]=f2bf(a0.y); ub.h[2]=f2bf(a0.z); ub.h[3]=f2bf(a0.w);
                ub.h[4]=f2bf(a1.x); ub.h[5]=f2bf(a1.y); ub.h[6]=f2bf(a1.z); ub.h[7]=f2bf(a1.w);
                acc[tt] = __builtin_amdgcn_mfma_f32_16x16x32_bf16(
                              afr[dp], ub.s8, acc[tt], 0, 0, 0);
            }

            // stage slice q+3 into slot (q+3)%4 (WAR-safe: its readers passed
            // the barrier at step q-1)
            const int q3 = s*8 + dp + 3;
            if (q3 < nf*8) {
                const int f3 = ((q3 >> 3) == 0) ? f0 : f1;
                stage2(f3, (dp + 3) & 7, (dp + 3) & 3);
            }
        }
    }

    __syncthreads();   // all staging retired; reuse xl for epilogue

    // ---- epilogue: per-wave transpose [16n][36] -> float4 row stores ----
    {
        float* tp = xl + wid*576;
        #pragma unroll
        for (int tt = 0; tt < 2; ++tt)
            #pragma unroll
            for (int r = 0; r < 4; ++r) {
                float v = acc[tt][r];
                v = (v > 0.f) ? v : 0.01f*v;
                tp[(kq*4 + r)*36 + tt*16 + cc] = v;
            }
        #pragma unroll
        for (int p = 0; p < 2; ++p) {
            const int linear = p*64 + lane;
            const int nn = linear >> 3;          // 0..15
            const int c4 = linear & 7;           // 4-float chunk of 32 t
            const float4 vv = *(const float4*)(tp + nn*36 + c4*4);
            const size_t ob = (size_t)(BG + nn)*4369 + (size_t)fo*257
                            + 128*th + 32*wid + 4*c4;
            out[ob + 0] = vv.x; out[ob + 1] = vv.y;
            out[ob + 2] = vv.z; out[ob + 3] = vv.w;
        }
    }

    // ---- t = 256 edge column (th==1 blocks only), fp32 ----
    if (th == 1) {
        const int n = tid & 15;
        const int d = tid >> 4;
        const size_t xrow_bg = (size_t)BG * 32768;
        float p = 0.f;
        for (int s = 0; s < nf; ++s) {
            const int f = (s == 0) ? f0 : f1;
            const float* xr = x + xrow_bg + (size_t)d*32768 + (size_t)f*1024 + 1016;
            const float* wr = wt + (size_t)(g*16 + n)*8192 + (size_t)d*512 + f*16;
            #pragma unroll
            for (int w = 0; w < 8; ++w) p = fmaf(xr[w], wr[w], p);
        }
        p += __shfl_xor(p, 16);
        p += __shfl_xor(p, 32);
        if (lane < 16) red[wid][lane] = p;
        __syncthreads();
        if (tid < 16) {
            float v = red[0][tid] + red[1][tid] + red[2][tid] + red[3][tid];
            v = (v > 0.f) ? v : 0.01f*v;
            out[(size_t)(BG + tid)*4369 + (size_t)fo*257 + 256] = v;
        }
    }
}

extern "C" void kernel_launch(void* const* d_in, const int* in_sizes, int n_in,
                              void* d_out, int out_size, void* d_ws, size_t ws_size,
                              hipStream_t stream) {
    const float* x  = (const float*)d_in[0];
    const float* wt = (const float*)d_in[1];
    float* out      = (float*)d_out;
    dim3 grid(17, 8, 16);   // (fo, g, b*2+th)
    lconv8<<<grid, TPB, 0, stream>>>(x, wt, out);
}

// Round 9
// 107.304 us; speedup vs baseline: 1.4567x; 1.4567x over previous
//
#include <hip/hip_runtime.h>

// LinearConv2D fused v9: v8 with the register-spill fix.
// v8's __launch_bounds__(256,8) forced a 32-VGPR budget -> scratch spills
// (FETCH 212MB / WRITE 226MB, all spill traffic). v9 uses (256,6): ~85-VGPR
// budget, body needs ~60, no spill; LDS (17.9KB) still admits 8 blocks/CU
// and <=64 VGPRs admits 8 waves/SIMD, keeping v8's doubled occupancy.
// Everything else identical to v8 (verified correct, absmax 0.5):
// x[8,128,32,1024] f32, weight[128,16,32,16] f32 -> out[8,128,17,257] f32
// y[n,t] = sum_{f in {2fo-1,2fo}} sum_{d,w} x[b,g16+d,f,4t+w-8]*wt[g16+n,d,f,w]
// Grid (fo, g, b*2+th) = 2176 blocks; block = 256 thr = 4 waves.
// Slice = (f,d-pair) x tau[512th-8, 512th+536) as [2 rows][544 f32];
// ring of 4 slots staged 3 ahead via global_load_lds (OOB lanes source from
// zero-filled __device__ g_zeros; never EXEC-mask pass A), counted vmcnt
// across raw s_barriers. Wave wid owns t = 128th + 16*(2wid+tt) + cc.

typedef __attribute__((ext_vector_type(8))) short short8v;
typedef __attribute__((ext_vector_type(4))) float f32x4;

#define TPB 256

__device__ __attribute__((aligned(64))) float g_zeros[16];   // BSS: all-zero

static __device__ __forceinline__ short f2bf(float f) {   // RNE f32->bf16
    unsigned u = __builtin_bit_cast(unsigned, f);
    u += 0x7FFFu + ((u >> 16) & 1u);
    return (short)(u >> 16);
}

__global__ __launch_bounds__(TPB, 6) void lconv9(
    const float* __restrict__ x,   // [8,128,32,1024]
    const float* __restrict__ wt,  // [128,16,32,16]
    float* __restrict__ out)       // [8,128,17,257]
{
    __shared__ __attribute__((aligned(16))) float xl[4352]; // 4 slots x 1088
    __shared__ float red[4][16];

    const int fo = blockIdx.x, g = blockIdx.y;
    const int b  = blockIdx.z >> 1, th = blockIdx.z & 1;
    const int tid  = threadIdx.x;
    const int lane = tid & 63;
    const int wid  = __builtin_amdgcn_readfirstlane(tid >> 6);
    const int cc = lane & 15;          // fragment column (t or n)
    const int kq = lane >> 4;          // k-group 0..3

    int fvals[2]; int nf = 0;
    if (2*fo - 1 >= 0) fvals[nf++] = 2*fo - 1;
    if (2*fo < 32)     fvals[nf++] = 2*fo;
    const int f0 = fvals[0];
    const int f1 = (nf > 1) ? fvals[1] : f0;

    const int BG = b*128 + g*16;
    const int wlc = (g*16 + cc)*8192 + (kq>>1)*512 + 8*(kq&1);
    // slice-local read base: row(kq>>1)*544 + 4cc + 8*(kq&1) + 128*wid (+64*tt+j)
    const int rbase = (kq>>1)*544 + 4*cc + 8*(kq&1) + 128*wid;

    // stage one (f, d-pair) half-slice into ring slot; 2 VM instr per wave,
    // pass A unconditional exec (lane0 of each wave active -> correct LDS base).
    // chunk c: row r = c>=136, c16 = c-136r, tau0 = 4*c16 - 8 + 512*th;
    // OOB chunks (window pads) DMA zeros from g_zeros via per-lane SOURCE select.
    auto stage2 = [&](int f_, int dp_, int slot_) {
        {   // pass A: chunks 0..255
            const int c   = tid;
            const int r   = (c >= 136) ? 1 : 0;
            const int c16 = c - r*136;
            const int tau0 = 4*c16 - 8 + 512*th;
            const bool ok = (tau0 >= 0) & (tau0 <= 1020);
            const float* src = ok
                ? (x + ((size_t)((BG + 2*dp_ + r)*32 + f_))*1024 + tau0)
                : g_zeros;
            __builtin_amdgcn_global_load_lds(
                (const __attribute__((address_space(1))) void*)src,
                (__attribute__((address_space(3))) void*)&xl[slot_*1088 + 4*c],
                16, 0, 0);
        }
        {   // pass B: chunks 256..271 (row-1 tail), lanes 0..15 of EVERY wave
            // (idempotent identical writes; lane 0 active -> base correct)
            const int c16 = 120 + (lane & 15);
            const int tau0 = 4*c16 - 8 + 512*th;
            const bool ok = (tau0 >= 0) & (tau0 <= 1020);
            const float* src = ok
                ? (x + ((size_t)((BG + 2*dp_ + 1)*32 + f_))*1024 + tau0)
                : g_zeros;
            if (lane < 16)
                __builtin_amdgcn_global_load_lds(
                    (const __attribute__((address_space(1))) void*)src,
                    (__attribute__((address_space(3))) void*)&xl[slot_*1088 + 4*(256 + lane)],
                    16, 0, 0);
        }
    };

    // prologue: stage slices 0,1,2 (all f0)
    stage2(f0, 0, 0);
    stage2(f0, 1, 1);
    stage2(f0, 2, 2);

    f32x4 acc[2];
    acc[0] = (f32x4){0.f, 0.f, 0.f, 0.f};
    acc[1] = (f32x4){0.f, 0.f, 0.f, 0.f};

    __syncthreads();   // drains prologue

    short8v afr[8];

    for (int s = 0; s < nf; ++s) {
        const int f = (s == 0) ? f0 : f1;

        // A-frags for this f: 8 d-pairs, 32B/lane (L1/L2-hot). Compiler's own
        // waitcnt for these retires them without draining the slice DMAs.
        #pragma unroll
        for (int dp = 0; dp < 8; ++dp) {
            const float* wp = wt + wlc + dp*1024 + f*16;
            const float4 w0 = *(const float4*)wp;
            const float4 w1 = *(const float4*)(wp + 4);
            union { short8v s8; short h[8]; } u;
            u.h[0]=f2bf(w0.x); u.h[1]=f2bf(w0.y); u.h[2]=f2bf(w0.z); u.h[3]=f2bf(w0.w);
            u.h[4]=f2bf(w1.x); u.h[5]=f2bf(w1.y); u.h[6]=f2bf(w1.z); u.h[7]=f2bf(w1.w);
            afr[dp] = u.s8;
        }

        const bool tail = (s == nf - 1);
        #pragma unroll
        for (int dp = 0; dp < 8; ++dp) {
            // counted wait: retire own slice-q loads; keep q+1..q+3 in flight
            if (tail && dp == 6)      asm volatile("s_waitcnt vmcnt(2)" ::: "memory");
            else if (tail && dp == 7) asm volatile("s_waitcnt vmcnt(0)" ::: "memory");
            else                      asm volatile("s_waitcnt vmcnt(4)" ::: "memory");
            __builtin_amdgcn_sched_barrier(0);
            __builtin_amdgcn_s_barrier();

            const float* xp = xl + (dp & 3)*1088 + rbase;
            #pragma unroll
            for (int tt = 0; tt < 2; ++tt) {
                const float4 a0 = *(const float4*)(xp + 64*tt);
                const float4 a1 = *(const float4*)(xp + 64*tt + 4);
                union { short8v s8; short h[8]; } ub;
                ub.h[0]=f2bf(a0.x); ub.h[1]=f2bf(a0.y); ub.h[2]=f2bf(a0.z); ub.h[3]=f2bf(a0.w);
                ub.h[4]=f2bf(a1.x); ub.h[5]=f2bf(a1.y); ub.h[6]=f2bf(a1.z); ub.h[7]=f2bf(a1.w);
                acc[tt] = __builtin_amdgcn_mfma_f32_16x16x32_bf16(
                              afr[dp], ub.s8, acc[tt], 0, 0, 0);
            }

            // stage slice q+3 into slot (q+3)%4 (WAR-safe: its readers passed
            // the barrier at step q-1)
            const int q3 = s*8 + dp + 3;
            if (q3 < nf*8) {
                const int f3 = ((q3 >> 3) == 0) ? f0 : f1;
                stage2(f3, (dp + 3) & 7, (dp + 3) & 3);
            }
        }
    }

    __syncthreads();   // all staging retired; reuse xl for epilogue

    // ---- epilogue: per-wave transpose [16n][36] -> float4 row stores ----
    {
        float* tp = xl + wid*576;
        #pragma unroll
        for (int tt = 0; tt < 2; ++tt)
            #pragma unroll
            for (int r = 0; r < 4; ++r) {
                float v = acc[tt][r];
                v = (v > 0.f) ? v : 0.01f*v;
                tp[(kq*4 + r)*36 + tt*16 + cc] = v;
            }
        #pragma unroll
        for (int p = 0; p < 2; ++p) {
            const int linear = p*64 + lane;
            const int nn = linear >> 3;          // 0..15
            const int c4 = linear & 7;           // 4-float chunk of 32 t
            const float4 vv = *(const float4*)(tp + nn*36 + c4*4);
            const size_t ob = (size_t)(BG + nn)*4369 + (size_t)fo*257
                            + 128*th + 32*wid + 4*c4;
            out[ob + 0] = vv.x; out[ob + 1] = vv.y;
            out[ob + 2] = vv.z; out[ob + 3] = vv.w;
        }
    }

    // ---- t = 256 edge column (th==1 blocks only), fp32 ----
    if (th == 1) {
        const int n = tid & 15;
        const int d = tid >> 4;
        const size_t xrow_bg = (size_t)BG * 32768;
        float p = 0.f;
        for (int s = 0; s < nf; ++s) {
            const int f = (s == 0) ? f0 : f1;
            const float* xr = x + xrow_bg + (size_t)d*32768 + (size_t)f*1024 + 1016;
            const float* wr = wt + (size_t)(g*16 + n)*8192 + (size_t)d*512 + f*16;
            #pragma unroll
            for (int w = 0; w < 8; ++w) p = fmaf(xr[w], wr[w], p);
        }
        p += __shfl_xor(p, 16);
        p += __shfl_xor(p, 32);
        if (lane < 16) red[wid][lane] = p;
        __syncthreads();
        if (tid < 16) {
            float v = red[0][tid] + red[1][tid] + red[2][tid] + red[3][tid];
            v = (v > 0.f) ? v : 0.01f*v;
            out[(size_t)(BG + tid)*4369 + (size_t)fo*257 + 256] = v;
        }
    }
}

extern "C" void kernel_launch(void* const* d_in, const int* in_sizes, int n_in,
                              void* d_out, int out_size, void* d_ws, size_t ws_size,
                              hipStream_t stream) {
    const float* x  = (const float*)d_in[0];
    const float* wt = (const float*)d_in[1];
    float* out      = (float*)d_out;
    dim3 grid(17, 8, 16);   // (fo, g, b*2+th)
    lconv9<<<grid, TPB, 0, stream>>>(x, wt, out);
}

// Round 11
// 68.468 us; speedup vs baseline: 2.2830x; 1.5672x over previous
//
#include <hip/hip_runtime.h>

// LinearConv2D fused v11: EXACT v9 body (verified correct twice: v8, v9)
// with ONE change: __launch_bounds__(256,4) instead of (256,6).
// Spill evidence: (256,8)->32 VGPR +226MB spill WRITE; (256,6)->40 VGPR
// +168MB; (256,4) never spilled (v5:56, v6:64 VGPR, WRITE ~20MB). <=64 VGPR
// is the HW step admitting 8 waves/SIMD (m69); launch_bounds is only a
// floor for the allocator -- residency follows the actual allocation, so
// LDS 17.9KB + grid 2176 (8.5 blocks/CU) can still reach ~8 blocks/CU.
// x[8,128,32,1024] f32, weight[128,16,32,16] f32 -> out[8,128,17,257] f32
// y[n,t] = sum_{f in {2fo-1,2fo}} sum_{d,w} x[b,g16+d,f,4t+w-8]*wt[g16+n,d,f,w]
// Grid (fo, g, b*2+th); block 256 thr = 4 waves; slice (f,d-pair) as
// [2][544] f32, ring of 4 slots staged 3 ahead via global_load_lds, counted
// vmcnt across raw s_barriers. OOB pad lanes DMA zeros from g_zeros
// (per-lane SOURCE select; never EXEC-mask pass A -- LDS dest base is
// readfirstlane + lane*16).

typedef __attribute__((ext_vector_type(8))) short short8v;
typedef __attribute__((ext_vector_type(4))) float f32x4;

#define TPB 256

__device__ __attribute__((aligned(64))) float g_zeros[16];   // BSS: all-zero

static __device__ __forceinline__ short f2bf(float f) {   // RNE f32->bf16
    unsigned u = __builtin_bit_cast(unsigned, f);
    u += 0x7FFFu + ((u >> 16) & 1u);
    return (short)(u >> 16);
}

__global__ __launch_bounds__(TPB, 4) void lconv11(
    const float* __restrict__ x,   // [8,128,32,1024]
    const float* __restrict__ wt,  // [128,16,32,16]
    float* __restrict__ out)       // [8,128,17,257]
{
    __shared__ __attribute__((aligned(16))) float xl[4352]; // 4 slots x 1088
    __shared__ float red[4][16];

    const int fo = blockIdx.x, g = blockIdx.y;
    const int b  = blockIdx.z >> 1, th = blockIdx.z & 1;
    const int tid  = threadIdx.x;
    const int lane = tid & 63;
    const int wid  = __builtin_amdgcn_readfirstlane(tid >> 6);
    const int cc = lane & 15;          // fragment column (t or n)
    const int kq = lane >> 4;          // k-group 0..3

    int fvals[2]; int nf = 0;
    if (2*fo - 1 >= 0) fvals[nf++] = 2*fo - 1;
    if (2*fo < 32)     fvals[nf++] = 2*fo;
    const int f0 = fvals[0];
    const int f1 = (nf > 1) ? fvals[1] : f0;

    const int BG = b*128 + g*16;
    const int wlc = (g*16 + cc)*8192 + (kq>>1)*512 + 8*(kq&1);
    // slice-local read base: row(kq>>1)*544 + 4cc + 8*(kq&1) + 128*wid (+64*tt+j)
    const int rbase = (kq>>1)*544 + 4*cc + 8*(kq&1) + 128*wid;

    // stage one (f, d-pair) half-slice into ring slot; 2 VM instr per wave,
    // pass A unconditional exec (lane0 of each wave active -> correct LDS base).
    // chunk c: row r = c>=136, c16 = c-136r, tau0 = 4*c16 - 8 + 512*th;
    // OOB chunks (window pads) DMA zeros from g_zeros via per-lane SOURCE select.
    auto stage2 = [&](int f_, int dp_, int slot_) {
        {   // pass A: chunks 0..255
            const int c   = tid;
            const int r   = (c >= 136) ? 1 : 0;
            const int c16 = c - r*136;
            const int tau0 = 4*c16 - 8 + 512*th;
            const bool ok = (tau0 >= 0) & (tau0 <= 1020);
            const float* src = ok
                ? (x + ((size_t)((BG + 2*dp_ + r)*32 + f_))*1024 + tau0)
                : g_zeros;
            __builtin_amdgcn_global_load_lds(
                (const __attribute__((address_space(1))) void*)src,
                (__attribute__((address_space(3))) void*)&xl[slot_*1088 + 4*c],
                16, 0, 0);
        }
        {   // pass B: chunks 256..271 (row-1 tail), lanes 0..15 of EVERY wave
            // (idempotent identical writes; lane 0 active -> base correct)
            const int c16 = 120 + (lane & 15);
            const int tau0 = 4*c16 - 8 + 512*th;
            const bool ok = (tau0 >= 0) & (tau0 <= 1020);
            const float* src = ok
                ? (x + ((size_t)((BG + 2*dp_ + 1)*32 + f_))*1024 + tau0)
                : g_zeros;
            if (lane < 16)
                __builtin_amdgcn_global_load_lds(
                    (const __attribute__((address_space(1))) void*)src,
                    (__attribute__((address_space(3))) void*)&xl[slot_*1088 + 4*(256 + lane)],
                    16, 0, 0);
        }
    };

    // prologue: stage slices 0,1,2 (all f0)
    stage2(f0, 0, 0);
    stage2(f0, 1, 1);
    stage2(f0, 2, 2);

    f32x4 acc[2];
    acc[0] = (f32x4){0.f, 0.f, 0.f, 0.f};
    acc[1] = (f32x4){0.f, 0.f, 0.f, 0.f};

    __syncthreads();   // drains prologue

    short8v afr[8];

    for (int s = 0; s < nf; ++s) {
        const int f = (s == 0) ? f0 : f1;

        // A-frags for this f: 8 d-pairs, 32B/lane (L1/L2-hot). Compiler's own
        // waitcnt for these retires them without draining the slice DMAs.
        #pragma unroll
        for (int dp = 0; dp < 8; ++dp) {
            const float* wp = wt + wlc + dp*1024 + f*16;
            const float4 w0 = *(const float4*)wp;
            const float4 w1 = *(const float4*)(wp + 4);
            union { short8v s8; short h[8]; } u;
            u.h[0]=f2bf(w0.x); u.h[1]=f2bf(w0.y); u.h[2]=f2bf(w0.z); u.h[3]=f2bf(w0.w);
            u.h[4]=f2bf(w1.x); u.h[5]=f2bf(w1.y); u.h[6]=f2bf(w1.z); u.h[7]=f2bf(w1.w);
            afr[dp] = u.s8;
        }

        const bool tail = (s == nf - 1);
        #pragma unroll
        for (int dp = 0; dp < 8; ++dp) {
            // counted wait: retire own slice-q loads; keep q+1..q+3 in flight
            if (tail && dp == 6)      asm volatile("s_waitcnt vmcnt(2)" ::: "memory");
            else if (tail && dp == 7) asm volatile("s_waitcnt vmcnt(0)" ::: "memory");
            else                      asm volatile("s_waitcnt vmcnt(4)" ::: "memory");
            __builtin_amdgcn_sched_barrier(0);
            __builtin_amdgcn_s_barrier();

            const float* xp = xl + (dp & 3)*1088 + rbase;
            #pragma unroll
            for (int tt = 0; tt < 2; ++tt) {
                const float4 a0 = *(const float4*)(xp + 64*tt);
                const float4 a1 = *(const float4*)(xp + 64*tt + 4);
                union { short8v s8; short h[8]; } ub;
                ub.h[0]=f2bf(a0.x); ub.h[1]=f2bf(a0.y); ub.h[2]=f2bf(a0.z); ub.h[3]=f2bf(a0.w);
                ub.h[4]=f2bf(a1.x); ub.h[5]=f2bf(a1.y); ub.h[6]=f2bf(a1.z); ub.h[7]=f2bf(a1.w);
                acc[tt] = __builtin_amdgcn_mfma_f32_16x16x32_bf16(
                              afr[dp], ub.s8, acc[tt], 0, 0, 0);
            }

            // stage slice q+3 into slot (q+3)%4 (WAR-safe: its readers passed
            // the barrier at step q-1)
            const int q3 = s*8 + dp + 3;
            if (q3 < nf*8) {
                const int f3 = ((q3 >> 3) == 0) ? f0 : f1;
                stage2(f3, (dp + 3) & 7, (dp + 3) & 3);
            }
        }
    }

    __syncthreads();   // all staging retired; reuse xl for epilogue

    // ---- epilogue: per-wave transpose [16n][36] -> float4 row stores ----
    {
        float* tp = xl + wid*576;
        #pragma unroll
        for (int tt = 0; tt < 2; ++tt)
            #pragma unroll
            for (int r = 0; r < 4; ++r) {
                float v = acc[tt][r];
                v = (v > 0.f) ? v : 0.01f*v;
                tp[(kq*4 + r)*36 + tt*16 + cc] = v;
            }
        #pragma unroll
        for (int p = 0; p < 2; ++p) {
            const int linear = p*64 + lane;
            const int nn = linear >> 3;          // 0..15
            const int c4 = linear & 7;           // 4-float chunk of 32 t
            const float4 vv = *(const float4*)(tp + nn*36 + c4*4);
            const size_t ob = (size_t)(BG + nn)*4369 + (size_t)fo*257
                            + 128*th + 32*wid + 4*c4;
            out[ob + 0] = vv.x; out[ob + 1] = vv.y;
            out[ob + 2] = vv.z; out[ob + 3] = vv.w;
        }
    }

    // ---- t = 256 edge column (th==1 blocks only), fp32 ----
    if (th == 1) {
        const int n = tid & 15;
        const int d = tid >> 4;
        const size_t xrow_bg = (size_t)BG * 32768;
        float p = 0.f;
        for (int s = 0; s < nf; ++s) {
            const int f = (s == 0) ? f0 : f1;
            const float* xr = x + xrow_bg + (size_t)d*32768 + (size_t)f*1024 + 1016;
            const float* wr = wt + (size_t)(g*16 + n)*8192 + (size_t)d*512 + f*16;
            #pragma unroll
            for (int w = 0; w < 8; ++w) p = fmaf(xr[w], wr[w], p);
        }
        p += __shfl_xor(p, 16);
        p += __shfl_xor(p, 32);
        if (lane < 16) red[wid][lane] = p;
        __syncthreads();
        if (tid < 16) {
            float v = red[0][tid] + red[1][tid] + red[2][tid] + red[3][tid];
            v = (v > 0.f) ? v : 0.01f*v;
            out[(size_t)(BG + tid)*4369 + (size_t)fo*257 + 256] = v;
        }
    }
}

extern "C" void kernel_launch(void* const* d_in, const int* in_sizes, int n_in,
                              void* d_out, int out_size, void* d_ws, size_t ws_size,
                              hipStream_t stream) {
    const float* x  = (const float*)d_in[0];
    const float* wt = (const float*)d_in[1];
    float* out      = (float*)d_out;
    dim3 grid(17, 8, 16);   // (fo, g, b*2+th)
    lconv11<<<grid, TPB, 0, stream>>>(x, wt, out);
}

// Round 12
// 61.474 us; speedup vs baseline: 2.5427x; 1.1138x over previous
//
#include <hip/hip_runtime.h>

// LinearConv2D fused v12: K=64 barrier-steps (d-quad slices), full-t blocks,
// ring-3 LDS staged 2 ahead with uniform counted vmcnt(8).
// x[8,128,32,1024] f32, weight[128,16,32,16] f32 -> out[8,128,17,257] f32
// y[n,t] = sum_{f in {2fo-1,2fo}} sum_{d,w} x[b,g16+d,f,4t+w-8]*wt[g16+n,d,f,w]
// Grid (fo,g,b) = 1088 blocks, 256 thr = 4 waves, acc[4] (64 t/wave).
// Slice q (q = 4s+dq) = d-quad (4 rows) of f = fvals[q>>2]:
//   LDS [4 rows][1088 f32] (row = 8 pad + 1024 + pads), slot = q%3 (52.2 KB).
// Stage = 8 gl_lds/wave: 4 full passes (j=tid) + 4 tail passes (lane<16,
//   lane-linear dest); OOB pads DMA zeros from g_zeros (per-lane SOURCE
//   select, exec never masks lane 0 of a full pass).
// Schedule/wave: wait vmcnt(8) [vmcnt(0) at last step] -> barrier -> compute
//   (2 k-slices x 4 t-tiles = 8 MFMA) -> [q==3: load f1 weights] -> stage(q+2).
// Weight loads issued before stage(q+2) keep retirement in-order => the
// uniform vmcnt(8) retires them exactly before first use (no drain).

typedef __attribute__((ext_vector_type(8))) short short8v;
typedef __attribute__((ext_vector_type(4))) float f32x4;

#define TPB 256

__device__ __attribute__((aligned(64))) float g_zeros[16];   // BSS: all-zero

static __device__ __forceinline__ short f2bf(float f) {   // RNE f32->bf16
    unsigned u = __builtin_bit_cast(unsigned, f);
    u += 0x7FFFu + ((u >> 16) & 1u);
    return (short)(u >> 16);
}

__global__ __launch_bounds__(TPB, 3) void lconv12(
    const float* __restrict__ x,   // [8,128,32,1024]
    const float* __restrict__ wt,  // [128,16,32,16]
    float* __restrict__ out)       // [8,128,17,257]
{
    __shared__ __attribute__((aligned(16))) float xl[13056]; // 3 slots x 4352
    __shared__ float red[4][16];

    const int fo = blockIdx.x, g = blockIdx.y, b = blockIdx.z;
    const int tid  = threadIdx.x;
    const int lane = tid & 63;
    const int wid  = __builtin_amdgcn_readfirstlane(tid >> 6);
    const int cc = lane & 15;          // fragment column (t or n)
    const int kq = lane >> 4;          // k-group 0..3

    int fvals[2]; int nf = 0;
    if (2*fo - 1 >= 0) fvals[nf++] = 2*fo - 1;
    if (2*fo < 32)     fvals[nf++] = 2*fo;

    const int BG = b*128 + g*16;
    const int wlc = (g*16 + cc)*8192 + (kq>>1)*512 + 8*(kq&1);
    // read base: row(2jj + (kq>>1))*1088 + 64T + 4cc + 8(kq&1), T = 4wid+tt
    const int rbase = (kq>>1)*1088 + 4*cc + 8*(kq&1) + 256*wid;

    // ---- stage slice q_: d-quad (q_&3) of f=fvals[q_>>2] into slot q_%3 ----
    auto stage = [&](int q_) {
        const int f_ = fvals[q_ >> 2];
        const int d0 = (q_ & 3) * 4;
        float* dst = xl + (q_ % 3) * 4352;
        // full passes: row k, chunks j=tid (tau0 = 4*tid-8; tid<2 -> left pad)
        const float* srcA = x + (size_t)(BG + d0)*32768 + (size_t)f_*1024
                              + (4*tid - 8);
        #pragma unroll
        for (int k = 0; k < 4; ++k) {
            const float* src = (tid >= 2) ? (srcA + k*32768) : g_zeros;
            __builtin_amdgcn_global_load_lds(
                (const __attribute__((address_space(1))) void*)src,
                (__attribute__((address_space(3))) void*)&dst[k*1088 + 4*tid],
                16, 0, 0);
        }
        // tail passes: row k, chunks j=256..271 (lane<16 of EVERY wave,
        // idempotent; dest lane-linear within each instruction)
        const int jB  = 256 + (lane & 15);
        const int tauB = 4*jB - 8;               // 1016..1076; >1020 -> pad
        #pragma unroll
        for (int k = 0; k < 4; ++k) {
            const float* src = (tauB <= 1020)
                ? (x + (size_t)(BG + d0 + k)*32768 + (size_t)f_*1024 + tauB)
                : g_zeros;
            if (lane < 16)
                __builtin_amdgcn_global_load_lds(
                    (const __attribute__((address_space(1))) void*)src,
                    (__attribute__((address_space(3))) void*)&dst[k*1088 + 4*jB],
                    16, 0, 0);
        }
    };

    // ---- weight fragments for one f: 8 d-pairs, 32B/lane ----
    auto loadW = [&](short8v (&afr_)[8], int f_) {
        #pragma unroll
        for (int dp = 0; dp < 8; ++dp) {
            const float* wp = wt + wlc + dp*1024 + f_*16;
            const float4 w0 = *(const float4*)wp;
            const float4 w1 = *(const float4*)(wp + 4);
            union { short8v s8; short h[8]; } u;
            u.h[0]=f2bf(w0.x); u.h[1]=f2bf(w0.y); u.h[2]=f2bf(w0.z); u.h[3]=f2bf(w0.w);
            u.h[4]=f2bf(w1.x); u.h[5]=f2bf(w1.y); u.h[6]=f2bf(w1.z); u.h[7]=f2bf(w1.w);
            afr_[dp] = u.s8;
        }
    };

    short8v afrA[8], afrB[8];
    loadW(afrA, fvals[0]);      // issued BEFORE prologue stages (in-order)
    stage(0);
    stage(1);

    f32x4 acc[4];
    #pragma unroll
    for (int t = 0; t < 4; ++t) acc[t] = (f32x4){0.f, 0.f, 0.f, 0.f};

    // one f's 4 steps; s is a call-site constant (inlined) so afr_ keeps
    // compile-time identity (no runtime-indexed register arrays)
    auto do_f = [&](const short8v (&afr_)[8], int s) {
        #pragma unroll
        for (int dq = 0; dq < 4; ++dq) {
            const int q = 4*s + dq;
            if (q == 4*nf - 1) asm volatile("s_waitcnt vmcnt(0)" ::: "memory");
            else               asm volatile("s_waitcnt vmcnt(8)" ::: "memory");
            __builtin_amdgcn_sched_barrier(0);
            __builtin_amdgcn_s_barrier();

            const float* xp = xl + (q % 3)*4352 + rbase;
            #pragma unroll
            for (int jj = 0; jj < 2; ++jj) {
                const float* xr = xp + jj*2176;
                #pragma unroll
                for (int tt = 0; tt < 4; ++tt) {
                    const float4 a0 = *(const float4*)(xr + 64*tt);
                    const float4 a1 = *(const float4*)(xr + 64*tt + 4);
                    union { short8v s8; short h[8]; } ub;
                    ub.h[0]=f2bf(a0.x); ub.h[1]=f2bf(a0.y); ub.h[2]=f2bf(a0.z); ub.h[3]=f2bf(a0.w);
                    ub.h[4]=f2bf(a1.x); ub.h[5]=f2bf(a1.y); ub.h[6]=f2bf(a1.z); ub.h[7]=f2bf(a1.w);
                    acc[tt] = __builtin_amdgcn_mfma_f32_16x16x32_bf16(
                                  afr_[2*dq + jj], ub.s8, acc[tt], 0, 0, 0);
                }
            }
            // f1 weights issued BEFORE stage(q+2) so in-order retirement keeps
            // the uniform vmcnt(8) schedule drain-free
            if (s == 0 && nf == 2 && dq == 3) loadW(afrB, fvals[1]);
            if (q + 2 <= 4*nf - 1) stage(q + 2);
        }
    };

    do_f(afrA, 0);
    if (nf == 2) do_f(afrB, 1);

    __syncthreads();   // everything retired; reuse xl for epilogue

    // ---- epilogue: per-wave transpose [16n][68] -> coalesced row stores ----
    {
        float* tp = xl + wid*1088;
        #pragma unroll
        for (int tt = 0; tt < 4; ++tt)
            #pragma unroll
            for (int r = 0; r < 4; ++r) {
                float v = acc[tt][r];
                v = (v > 0.f) ? v : 0.01f*v;
                tp[(kq*4 + r)*68 + tt*16 + cc] = v;
            }
        #pragma unroll
        for (int p = 0; p < 4; ++p) {
            const int linear = p*64 + lane;
            const int nn = linear >> 4;          // 0..15
            const int c4 = linear & 15;          // 16B chunk of local t
            const float4 vv = *(const float4*)(tp + nn*68 + c4*4);
            const size_t ob = (size_t)(BG + nn)*4369 + (size_t)fo*257
                            + wid*64 + c4*4;
            out[ob + 0] = vv.x; out[ob + 1] = vv.y;
            out[ob + 2] = vv.z; out[ob + 3] = vv.w;
        }
    }

    // ---- t = 256 edge column, fp32 (window taps w=0..7 only) ----
    {
        const int n = tid & 15;
        const int d = tid >> 4;
        const size_t xrow_bg = (size_t)BG * 32768;
        float p = 0.f;
        for (int s = 0; s < nf; ++s) {
            const int f = fvals[s];
            const float* xr = x + xrow_bg + (size_t)d*32768 + (size_t)f*1024 + 1016;
            const float* wr = wt + (size_t)(g*16 + n)*8192 + (size_t)d*512 + f*16;
            #pragma unroll
            for (int w = 0; w < 8; ++w) p = fmaf(xr[w], wr[w], p);
        }
        p += __shfl_xor(p, 16);
        p += __shfl_xor(p, 32);
        if (lane < 16) red[wid][lane] = p;
        __syncthreads();
        if (tid < 16) {
            float v = red[0][tid] + red[1][tid] + red[2][tid] + red[3][tid];
            v = (v > 0.f) ? v : 0.01f*v;
            out[(size_t)(BG + tid)*4369 + (size_t)fo*257 + 256] = v;
        }
    }
}

extern "C" void kernel_launch(void* const* d_in, const int* in_sizes, int n_in,
                              void* d_out, int out_size, void* d_ws, size_t ws_size,
                              hipStream_t stream) {
    const float* x  = (const float*)d_in[0];
    const float* wt = (const float*)d_in[1];
    float* out      = (float*)d_out;
    dim3 grid(17, 8, 8);   // (fo, g, b)
    lconv12<<<grid, TPB, 0, stream>>>(x, wt, out);
}

// Round 13
// 55.595 us; speedup vs baseline: 2.8116x; 1.1057x over previous
//
#include <hip/hip_runtime.h>
#include <hip/hip_bf16.h>

// LinearConv2D fused v13: barrier-free register-staged MFMA pipeline.
// x[8,128,32,1024] f32, weight[128,16,32,16] f32 -> out[8,128,17,257] f32
// y[n,t] = sum_{f in {2fo-1,2fo}} sum_{d,w} x[b,g16+d,f,4t+w-8]*wt[g16+n,d,f,w]
// Grid (fo,g,b)=1088 blocks x 256 thr = 4 independent waves (NO main-loop
// barriers / NO main-loop LDS). Wave wid: 16n x 64t (tiles T=4wid+tt).
// k-slice q = (f=q>=8?f1:f0, d-pair dp=q&7): per slice 8 x-dwordx4 + 2
// w-dwordx4 into 2-deep named rotation buffers (pa/pb); cvt f32->bf16 via
// __float22bfloat162_rn pairs (v_cvt_pk_bf16_f32); 4 MFMA (A=weights frag,
// B=x frag; maps verified in v4/v5).
// Window edges: per-lane tau0 clamped to [0,1016] -> only output columns
// t in {0,1,255} are garbage (MFMA column isolation); exact fp32 fixup
// epilogue recomputes t in {0,1,255,256} and patches via the LDS transpose.

typedef __attribute__((ext_vector_type(8))) short short8v;
typedef __attribute__((ext_vector_type(4))) float f32x4;

#define TPB 256

static __device__ __forceinline__ short8v cvt8(const f32x4 a, const f32x4 b) {
    union { short8v s8; __hip_bfloat162 h2[4]; } u;
    u.h2[0] = __float22bfloat162_rn(make_float2(a.x, a.y));
    u.h2[1] = __float22bfloat162_rn(make_float2(a.z, a.w));
    u.h2[2] = __float22bfloat162_rn(make_float2(b.x, b.y));
    u.h2[3] = __float22bfloat162_rn(make_float2(b.z, b.w));
    return u.s8;
}

struct SliceBuf {
    f32x4 xv[4][2];   // [tile][a0/a1] -- all accesses fully unrolled/static
    f32x4 wv[2];
};

__global__ __launch_bounds__(TPB, 3) void lconv13(
    const float* __restrict__ x,   // [8,128,32,1024]
    const float* __restrict__ wt,  // [128,16,32,16]
    float* __restrict__ out)       // [8,128,17,257]
{
    __shared__ __attribute__((aligned(16))) float xl[4352];  // 4 waves x [16][68]
    __shared__ f32x4 redl[4][16];

    const int fo = blockIdx.x, g = blockIdx.y, b = blockIdx.z;
    const int tid  = threadIdx.x;
    const int lane = tid & 63;
    const int wid  = __builtin_amdgcn_readfirstlane(tid >> 6);
    const int cc = lane & 15;          // fragment column (t or n)
    const int kq = lane >> 4;          // k-group 0..3

    int f0, f1, nf;
    if (fo == 0)       { f0 = 0;        f1 = 0;    nf = 1; }
    else if (fo == 16) { f0 = 31;       f1 = 31;   nf = 1; }
    else               { f0 = 2*fo - 1; f1 = 2*fo; nf = 2; }
    const int NS = nf * 8;

    const int BG = b*128 + g*16;

    // per-lane x offsets (f32 elements) for the 8 x-loads of one slice
    int voffx[4][2];
    #pragma unroll
    for (int tt = 0; tt < 4; ++tt) {
        int tau0 = 64*(4*wid + tt) + 4*cc + 8*(kq & 1) - 8;
        tau0 = tau0 < 0 ? 0 : (tau0 > 1016 ? 1016 : tau0);   // edge clamp
        voffx[tt][0] = (kq >> 1)*32768 + tau0;
        voffx[tt][1] = voffx[tt][0] + 4;
    }
    // per-lane weight offset relative to (wt + g16*8192 + dp*1024 + f*16)
    const int voffw = cc*8192 + (kq >> 1)*512 + 8*(kq & 1);

    auto issueb = [&](SliceBuf& P, int q_) {
        const int dp_ = q_ & 7;
        const int f_  = (q_ >= 8) ? f1 : f0;
        const float* xb = x + (size_t)(BG + 2*dp_)*32768 + (size_t)f_*1024;
        const float* wb = wt + (size_t)(g*16)*8192 + (size_t)dp_*1024
                             + (size_t)f_*16;
        #pragma unroll
        for (int tt = 0; tt < 4; ++tt) {
            P.xv[tt][0] = *(const f32x4*)(xb + voffx[tt][0]);
            P.xv[tt][1] = *(const f32x4*)(xb + voffx[tt][1]);
        }
        P.wv[0] = *(const f32x4*)(wb + voffw);
        P.wv[1] = *(const f32x4*)(wb + voffw + 4);
    };

    f32x4 acc[4];
    #pragma unroll
    for (int t = 0; t < 4; ++t) acc[t] = (f32x4){0.f, 0.f, 0.f, 0.f};

    auto stepb = [&](SliceBuf& P, int q_, int qn) {
        const short8v wf = cvt8(P.wv[0], P.wv[1]);
        short8v xf[4];
        #pragma unroll
        for (int tt = 0; tt < 4; ++tt) xf[tt] = cvt8(P.xv[tt][0], P.xv[tt][1]);
        if (qn < NS) issueb(P, qn);        // prefetch 2 slices ahead
        #pragma unroll
        for (int tt = 0; tt < 4; ++tt)
            acc[tt] = __builtin_amdgcn_mfma_f32_16x16x32_bf16(
                          wf, xf[tt], acc[tt], 0, 0, 0);
    };

    SliceBuf pa, pb;
    issueb(pa, 0);
    issueb(pb, 1);
    for (int q = 0; q < NS; q += 2) {
        stepb(pa, q,     q + 2);
        stepb(pb, q + 1, q + 3);
    }

    // ---- epilogue 1: acc -> per-wave LDS transpose tile [16n][68] ----
    {
        float* tp = xl + wid*1088;
        #pragma unroll
        for (int tt = 0; tt < 4; ++tt)
            #pragma unroll
            for (int r = 0; r < 4; ++r) {
                float v = acc[tt][r];
                v = (v > 0.f) ? v : 0.01f*v;
                tp[(kq*4 + r)*68 + tt*16 + cc] = v;
            }
    }
    __syncthreads();

    // ---- epilogue 2: exact fp32 fixup for t in {0,1,255,256} ----
    {
        const int n  = tid & 15;
        const int dd = tid >> 4;
        f32x4 p4 = (f32x4){0.f, 0.f, 0.f, 0.f};
        for (int s = 0; s < nf; ++s) {
            const int f = (s == 0) ? f0 : f1;
            const float* xr = x + (size_t)(BG + dd)*32768 + (size_t)f*1024;
            const float* wr = wt + (size_t)(g*16 + n)*8192 + (size_t)dd*512
                                 + (size_t)f*16;
            #pragma unroll
            for (int w = 0; w < 16; ++w) {
                const float wv = wr[w];
                if (w >= 8)  p4.x = fmaf(xr[w - 8],    wv, p4.x);  // t=0
                if (w >= 4)  p4.y = fmaf(xr[w - 4],    wv, p4.y);  // t=1
                if (w < 12)  p4.z = fmaf(xr[1012 + w], wv, p4.z);  // t=255
                if (w < 8)   p4.w = fmaf(xr[1016 + w], wv, p4.w);  // t=256
            }
        }
        p4.x += __shfl_xor(p4.x, 16); p4.x += __shfl_xor(p4.x, 32);
        p4.y += __shfl_xor(p4.y, 16); p4.y += __shfl_xor(p4.y, 32);
        p4.z += __shfl_xor(p4.z, 16); p4.z += __shfl_xor(p4.z, 32);
        p4.w += __shfl_xor(p4.w, 16); p4.w += __shfl_xor(p4.w, 32);
        if (lane < 16) redl[wid][lane] = p4;
    }
    __syncthreads();
    if (tid < 16) {
        f32x4 a = redl[0][tid], bb = redl[1][tid], c = redl[2][tid], d = redl[3][tid];
        float t0   = a.x + bb.x + c.x + d.x;
        float t1   = a.y + bb.y + c.y + d.y;
        float t255 = a.z + bb.z + c.z + d.z;
        float t256 = a.w + bb.w + c.w + d.w;
        t0   = (t0   > 0.f) ? t0   : 0.01f*t0;
        t1   = (t1   > 0.f) ? t1   : 0.01f*t1;
        t255 = (t255 > 0.f) ? t255 : 0.01f*t255;
        t256 = (t256 > 0.f) ? t256 : 0.01f*t256;
        xl[tid*68 + 0] = t0;                    // wave-0 region, local t=0
        xl[tid*68 + 1] = t1;                    // local t=1
        xl[3*1088 + tid*68 + 63] = t255;        // wave-3 region, local t=63
        out[(size_t)(BG + tid)*4369 + (size_t)fo*257 + 256] = t256;
    }
    __syncthreads();

    // ---- epilogue 3: coalesced row stores from LDS ----
    {
        const float* tp = xl + wid*1088;
        #pragma unroll
        for (int p = 0; p < 4; ++p) {
            const int linear = p*64 + lane;
            const int nn = linear >> 4;          // 0..15
            const int c4 = linear & 15;          // 4-float chunk of 64 t
            const float4 vv = *(const float4*)(tp + nn*68 + c4*4);
            const size_t ob = (size_t)(BG + nn)*4369 + (size_t)fo*257
                            + wid*64 + c4*4;
            out[ob + 0] = vv.x; out[ob + 1] = vv.y;
            out[ob + 2] = vv.z; out[ob + 3] = vv.w;
        }
    }
}

extern "C" void kernel_launch(void* const* d_in, const int* in_sizes, int n_in,
                              void* d_out, int out_size, void* d_ws, size_t ws_size,
                              hipStream_t stream) {
    const float* x  = (const float*)d_in[0];
    const float* wt = (const float*)d_in[1];
    float* out      = (float*)d_out;
    dim3 grid(17, 8, 8);   // (fo, g, b)
    lconv13<<<grid, TPB, 0, stream>>>(x, wt, out);
}